// Round 1
// baseline (902.450 us; speedup 1.0000x reference)
//
#include <hip/hip_runtime.h>
#include <math.h>

#define B_ 2
#define S_ 2048
#define DIM_ 512
#define H_ 8
#define DH_ 64
#define QR_ 8   // query rows per attention block

// ---------------------------------------------------------------------------
// Projection: C[r,c] = sum_k A[r,k] * W[c,k] + bias[c]   (A @ W^T + b)
// A: [B*S, DIM], W: [DIM, DIM] row-major. blockIdx.z selects Q/K/V.
// 64x64 tile, BK=32, 256 threads, 4x4 micro-tile per thread.
// ---------------------------------------------------------------------------
__global__ __launch_bounds__(256) void proj_kernel(
    const float* __restrict__ Ain, const float* __restrict__ Kin,
    const float* __restrict__ Wq, const float* __restrict__ bq,
    const float* __restrict__ Wk, const float* __restrict__ bk,
    const float* __restrict__ Wv, const float* __restrict__ bv,
    float* __restrict__ Qb, float* __restrict__ Kb, float* __restrict__ Vb)
{
    const int which = blockIdx.z;
    const float* A    = (which == 0) ? Ain : Kin;
    const float* W    = (which == 0) ? Wq : (which == 1 ? Wk : Wv);
    const float* bias = (which == 0) ? bq : (which == 1 ? bk : bv);
    float* C          = (which == 0) ? Qb : (which == 1 ? Kb : Vb);

    __shared__ float As[64][36];  // stride 36 floats = 144B: 16B-aligned rows, bank-spread
    __shared__ float Ws[64][36];

    const int tid = threadIdx.x;
    const int tm = blockIdx.x, tn = blockIdx.y;
    const int tr = tid >> 4, tc = tid & 15;

    float acc[4][4] = {};

    for (int k0 = 0; k0 < DIM_; k0 += 32) {
#pragma unroll
        for (int i = 0; i < 2; ++i) {
            int idx = tid + i * 256;          // 0..511 float4 slots (64 rows x 8)
            int r = idx >> 3, c4 = (idx & 7) << 2;
            float4 av = *(const float4*)&A[(size_t)(tm * 64 + r) * DIM_ + k0 + c4];
            float4 wv = *(const float4*)&W[(size_t)(tn * 64 + r) * DIM_ + k0 + c4];
            *(float4*)&As[r][c4] = av;
            *(float4*)&Ws[r][c4] = wv;
        }
        __syncthreads();
#pragma unroll
        for (int kk = 0; kk < 32; ++kk) {
            float a0 = As[tr * 4 + 0][kk];
            float a1 = As[tr * 4 + 1][kk];
            float a2 = As[tr * 4 + 2][kk];
            float a3 = As[tr * 4 + 3][kk];
            float w0 = Ws[tc * 4 + 0][kk];
            float w1 = Ws[tc * 4 + 1][kk];
            float w2 = Ws[tc * 4 + 2][kk];
            float w3 = Ws[tc * 4 + 3][kk];
            acc[0][0] += a0 * w0; acc[0][1] += a0 * w1; acc[0][2] += a0 * w2; acc[0][3] += a0 * w3;
            acc[1][0] += a1 * w0; acc[1][1] += a1 * w1; acc[1][2] += a1 * w2; acc[1][3] += a1 * w3;
            acc[2][0] += a2 * w0; acc[2][1] += a2 * w1; acc[2][2] += a2 * w2; acc[2][3] += a2 * w3;
            acc[3][0] += a3 * w0; acc[3][1] += a3 * w1; acc[3][2] += a3 * w2; acc[3][3] += a3 * w3;
        }
        __syncthreads();
    }

#pragma unroll
    for (int i = 0; i < 4; ++i) {
        int row = tm * 64 + tr * 4 + i;
#pragma unroll
        for (int j = 0; j < 4; ++j) {
            int col = tn * 64 + tc * 4 + j;
            C[(size_t)row * DIM_ + col] = acc[i][j] + bias[col];
        }
    }
}

// ---------------------------------------------------------------------------
// Fused attention: per block = one (head*batch n, 8-query-row tile).
// scores -> LDS, wave-parallel softmax, write attn weights once, PV from LDS.
// ---------------------------------------------------------------------------
__global__ __launch_bounds__(256) void attn_kernel(
    const float* __restrict__ Qb, const float* __restrict__ Kb,
    const float* __restrict__ Vb, const int* __restrict__ causp,
    float* __restrict__ outp, float* __restrict__ attnw)
{
    __shared__ float sc[QR_][S_ + 4];   // 8 x 2052 x 4B = 65.7 KB
    __shared__ float qs[QR_][DH_ + 4];

    const int qt = blockIdx.x;          // 0..S/QR-1
    const int n  = blockIdx.y;          // 0..15, n = h*B + b
    const int h = n / B_, b = n % B_;
    const int q0 = qt * QR_;
    const int tid = threadIdx.x;
    const int causal = causp[0];

    const float* Qn = Qb + (size_t)b * S_ * DIM_ + h * DH_;
    const float* Kn = Kb + (size_t)b * S_ * DIM_ + h * DH_;
    const float* Vn = Vb + (size_t)b * S_ * DIM_ + h * DH_;

    // stage Q tile (8 x 64 floats)
    for (int i = tid; i < QR_ * DH_ / 4; i += 256) {
        int r = i >> 4, c = (i & 15) << 2;
        *(float4*)&qs[r][c] = *(const float4*)&Qn[(size_t)(q0 + r) * DIM_ + c];
    }
    __syncthreads();

    const int kmax = causal ? (q0 + QR_) : S_;

    // ---- scores: sc[r][k] = (q_r . k_k) / 8 for k < kmax
    for (int idx = tid; idx < QR_ * kmax; idx += 256) {
        int r = idx & (QR_ - 1);
        int k = idx >> 3;
        const float* krow = &Kn[(size_t)k * DIM_];
        float s = 0.f;
#pragma unroll
        for (int c = 0; c < DH_; c += 4) {
            float4 qv = *(const float4*)&qs[r][c];
            float4 kv = *(const float4*)&krow[c];
            s += qv.x * kv.x + qv.y * kv.y + qv.z * kv.z + qv.w * kv.w;
        }
        sc[r][k] = s * 0.125f;
    }
    __syncthreads();

    // ---- softmax per row + stream normalized weights to global
    const int wave = tid >> 6, lane = tid & 63;
#pragma unroll
    for (int rr = 0; rr < 2; ++rr) {
        int r = wave * 2 + rr;
        int q = q0 + r;
        int L = causal ? (q + 1) : S_;   // valid keys (causal); pad masks are all-1

        float m = -INFINITY;
        for (int k = lane; k < L; k += 64) m = fmaxf(m, sc[r][k]);
#pragma unroll
        for (int off = 32; off > 0; off >>= 1) m = fmaxf(m, __shfl_xor(m, off));

        float ssum = 0.f;
        for (int k = lane; k < L; k += 64) {
            float p = __expf(sc[r][k] - m);
            sc[r][k] = p;
            ssum += p;
        }
#pragma unroll
        for (int off = 32; off > 0; off >>= 1) ssum += __shfl_xor(ssum, off);
        float inv = 1.f / ssum;

        float* wrow = attnw + ((size_t)(b * H_ + h) * S_ + q) * S_;
        for (int k = lane; k < S_; k += 64) {
            if (k < L) {
                float p = sc[r][k] * inv;
                sc[r][k] = p;
                wrow[k] = p;
            } else {
                wrow[k] = 0.f;
            }
        }
    }
    __syncthreads();

    // ---- PV: out[b, q, h*64+j] = sum_{k<L} p[k] * V[k, j]
    {
        int r = tid >> 5, jj = tid & 31;
        int q = q0 + r;
        int L = causal ? (q + 1) : S_;
        float acc0 = 0.f, acc1 = 0.f;
        int k = 0;
        for (; k + 4 <= L; k += 4) {
#pragma unroll
            for (int u = 0; u < 4; ++u) {
                float p = sc[r][k + u];
                acc0 += p * Vn[(size_t)(k + u) * DIM_ + jj];
                acc1 += p * Vn[(size_t)(k + u) * DIM_ + jj + 32];
            }
        }
        for (; k < L; ++k) {
            float p = sc[r][k];
            acc0 += p * Vn[(size_t)k * DIM_ + jj];
            acc1 += p * Vn[(size_t)k * DIM_ + jj + 32];
        }
        size_t orow = ((size_t)b * S_ + q) * DIM_ + h * DH_;
        outp[orow + jj] = acc0;
        outp[orow + jj + 32] = acc1;
    }
}

extern "C" void kernel_launch(void* const* d_in, const int* in_sizes, int n_in,
                              void* d_out, int out_size, void* d_ws, size_t ws_size,
                              hipStream_t stream) {
    const float* queries = (const float*)d_in[0];
    const float* keys    = (const float*)d_in[1];
    const float* Wq = (const float*)d_in[2];
    const float* bq = (const float*)d_in[3];
    const float* Wk = (const float*)d_in[4];
    const float* bk = (const float*)d_in[5];
    const float* Wv = (const float*)d_in[6];
    const float* bv = (const float*)d_in[7];
    const int*   caus = (const int*)d_in[8];

    float* Qb = (float*)d_ws;                       // [B*S, DIM] f32, 8 MB
    float* Kb = Qb + (size_t)B_ * S_ * DIM_;        // 8 MB
    float* Vb = Kb + (size_t)B_ * S_ * DIM_;        // 8 MB

    float* outp  = (float*)d_out;                   // [B, S, DIM]
    float* attnw = outp + (size_t)B_ * S_ * DIM_;   // [B, H, S, S]

    dim3 pgrid((B_ * S_) / 64, DIM_ / 64, 3);
    proj_kernel<<<pgrid, 256, 0, stream>>>(queries, keys, Wq, bq, Wk, bk, Wv, bv,
                                           Qb, Kb, Vb);

    dim3 agrid(S_ / QR_, H_ * B_);
    attn_kernel<<<agrid, 256, 0, stream>>>(Qb, Kb, Vb, caus, outp, attnw);
}

// Round 2
// 211.606 us; speedup vs baseline: 4.2648x; 4.2648x over previous
//
#include <hip/hip_runtime.h>
#include <math.h>

#define B_ 2
#define S_ 2048
#define DIM_ 512
#define H_ 8
#define DH_ 64
#define QBLK 32
#define KT 64

typedef __bf16 bf16x8 __attribute__((ext_vector_type(8)));
typedef float f32x4 __attribute__((ext_vector_type(4)));
typedef unsigned short ushort_t;
typedef ushort_t ushort8 __attribute__((ext_vector_type(8)));

__device__ __forceinline__ ushort_t f2bf(float f) {
    union { float f; unsigned u; } v; v.f = f;
    unsigned u = v.u;
    return (ushort_t)((u + 0x7FFFu + ((u >> 16) & 1u)) >> 16);
}

// ---------------------------------------------------------------------------
// f32 -> bf16 conversion for inputs and weights
// ---------------------------------------------------------------------------
__global__ __launch_bounds__(256) void convert_kernel(
    const float* __restrict__ q, const float* __restrict__ k,
    const float* __restrict__ wq, const float* __restrict__ wk,
    const float* __restrict__ wv,
    ushort_t* qbf, ushort_t* kbf, ushort_t* wqb, ushort_t* wkb, ushort_t* wvb)
{
    const float* src; ushort_t* dst; int n;
    switch (blockIdx.y) {
        case 0: src = q;  dst = qbf; n = B_ * S_ * DIM_; break;
        case 1: src = k;  dst = kbf; n = B_ * S_ * DIM_; break;
        case 2: src = wq; dst = wqb; n = DIM_ * DIM_; break;
        case 3: src = wk; dst = wkb; n = DIM_ * DIM_; break;
        default: src = wv; dst = wvb; n = DIM_ * DIM_; break;
    }
    int i4 = blockIdx.x * 256 + threadIdx.x;
    if (i4 * 4 >= n) return;
    float4 v = ((const float4*)src)[i4];
    ushort4 o;
    o.x = f2bf(v.x); o.y = f2bf(v.y); o.z = f2bf(v.z); o.w = f2bf(v.w);
    ((ushort4*)dst)[i4] = o;
}

// ---------------------------------------------------------------------------
// Projection via MFMA: C = A @ W^T + b. Direct-global fragment loads.
// which 0: queries->Qh (head-major bf16), 1: keys->Kh, 2: keys->Vt (transposed)
// Block: 64 rows x 64 cols (one head). 4 waves, wave w = rows w*16.
// ---------------------------------------------------------------------------
__global__ __launch_bounds__(256) void proj_mfma_kernel(
    const ushort_t* __restrict__ Qin, const ushort_t* __restrict__ Kin,
    const ushort_t* __restrict__ Wqb, const float* __restrict__ bq,
    const ushort_t* __restrict__ Wkb, const float* __restrict__ bk,
    const ushort_t* __restrict__ Wvb, const float* __restrict__ bv,
    ushort_t* __restrict__ Qh, ushort_t* __restrict__ Kh, ushort_t* __restrict__ Vt)
{
    __shared__ float T[64][68];   // transpose staging (which==2 only)

    const int which = blockIdx.z;
    const ushort_t* A = (which == 0) ? Qin : Kin;
    const ushort_t* W = (which == 0) ? Wqb : (which == 1 ? Wkb : Wvb);
    const float* bias = (which == 0) ? bq : (which == 1 ? bk : bv);

    const int r0 = blockIdx.x * 64;
    const int h  = blockIdx.y;
    const int c0 = h * DH_;
    const int tid = threadIdx.x;
    const int w = tid >> 6, l = tid & 63;
    const int lr = l & 15, lg = l >> 4;

    f32x4 acc[4] = {};
    const ushort_t* arow  = A + (size_t)(r0 + w * 16 + lr) * DIM_ + lg * 8;
    const ushort_t* wrow0 = W + (size_t)(c0 + lr) * DIM_ + lg * 8;

    for (int ks = 0; ks < DIM_ / 32; ++ks) {
        bf16x8 a = *(const bf16x8*)(arow + ks * 32);
#pragma unroll
        for (int ct = 0; ct < 4; ++ct) {
            bf16x8 bfr = *(const bf16x8*)(wrow0 + (size_t)ct * 16 * DIM_ + ks * 32);
            acc[ct] = __builtin_amdgcn_mfma_f32_16x16x32_bf16(a, bfr, acc[ct], 0, 0, 0);
        }
    }

    if (which < 2) {
        ushort_t* OUT = (which == 0) ? Qh : Kh;
#pragma unroll
        for (int ct = 0; ct < 4; ++ct) {
            int d = ct * 16 + lr;
            float bi = bias[c0 + d];
#pragma unroll
            for (int reg = 0; reg < 4; ++reg) {
                int rr = r0 + w * 16 + lg * 4 + reg;
                int bb = rr >> 11, s = rr & (S_ - 1);
                int n = h * B_ + bb;
                OUT[((size_t)n * S_ + s) * DH_ + d] = f2bf(acc[ct][reg] + bi);
            }
        }
    } else {
#pragma unroll
        for (int ct = 0; ct < 4; ++ct) {
            int d = ct * 16 + lr;
            float bi = bias[c0 + d];
#pragma unroll
            for (int reg = 0; reg < 4; ++reg)
                T[w * 16 + lg * 4 + reg][d] = acc[ct][reg] + bi;
        }
        __syncthreads();
        int d = tid & 63, sc = tid >> 6;
        int rr = r0 + sc * 16;
        int bb = rr >> 11, s = rr & (S_ - 1);
        int n = h * B_ + bb;
        ushort8 o[2];
#pragma unroll
        for (int i = 0; i < 16; ++i)
            ((ushort_t*)o)[i] = f2bf(T[sc * 16 + i][d]);
        ushort8* dst = (ushort8*)(Vt + ((size_t)n * DH_ + d) * S_ + s);
        dst[0] = o[0];
        dst[1] = o[1];
    }
}

// ---------------------------------------------------------------------------
// Fused attention, MFMA, two-pass (sum-of-exp, then recompute+write+PV).
// Block: QBLK=32 q-rows x one n=(h*B+b). 4 waves: qi=w>>1 (16 rows), kh=w&1.
// ---------------------------------------------------------------------------
__global__ __launch_bounds__(256) void attn_mfma_kernel(
    const ushort_t* __restrict__ Qh, const ushort_t* __restrict__ Kh,
    const ushort_t* __restrict__ Vt, const int* __restrict__ causp,
    float* __restrict__ outp, float* __restrict__ attnw)
{
    __shared__ float P_lds[QBLK][KT + 4];
    __shared__ float sumL[2][QBLK];

    const int bid = blockIdx.x;
    const int nb = (bid & 7) * 128 + (bid >> 3);   // XCD-bijective swizzle (1024%8==0)
    const int n = nb >> 6;
    const int qt = nb & 63;
    const int h = n / B_, b = n % B_;
    const int q0 = qt * QBLK;
    const int causal = causp[0];
    const int tid = threadIdx.x;
    const int w = tid >> 6, l = tid & 63;
    const int lr = l & 15, lg = l >> 4;
    const int qi = w >> 1, kh = w & 1;

    const int kmaxval = causal ? (q0 + QBLK) : S_;
    const int kend = ((kmaxval + KT - 1) / KT) * KT;

    const ushort_t* qrow = Qh + ((size_t)n * S_ + q0 + qi * 16 + lr) * DH_ + lg * 8;
    bf16x8 qa0 = *(const bf16x8*)(qrow);
    bf16x8 qa1 = *(const bf16x8*)(qrow + 32);

    const ushort_t* Kbase = Kh + (size_t)n * S_ * DH_;
    const int qrow0 = q0 + qi * 16 + lg * 4;

    // ---- pass 1: per-row sum of exp(s). No max subtraction: |s| is O(1),
    // exp cannot overflow; softmax is shift-invariant so result matches ref.
    float pl[4] = {0.f, 0.f, 0.f, 0.f};
    for (int kt = 0; kt < kend; kt += KT) {
        int kcA = kt + kh * 32;
        const ushort_t* kra = Kbase + (size_t)(kcA + lr) * DH_ + lg * 8;
        const ushort_t* krb = kra + (size_t)16 * DH_;
        f32x4 accA = {}, accB = {};
        accA = __builtin_amdgcn_mfma_f32_16x16x32_bf16(qa0, *(const bf16x8*)(kra),      accA, 0, 0, 0);
        accA = __builtin_amdgcn_mfma_f32_16x16x32_bf16(qa1, *(const bf16x8*)(kra + 32), accA, 0, 0, 0);
        accB = __builtin_amdgcn_mfma_f32_16x16x32_bf16(qa0, *(const bf16x8*)(krb),      accB, 0, 0, 0);
        accB = __builtin_amdgcn_mfma_f32_16x16x32_bf16(qa1, *(const bf16x8*)(krb + 32), accB, 0, 0, 0);
#pragma unroll
        for (int reg = 0; reg < 4; ++reg) {
            int qq = qrow0 + reg;
            int kA = kcA + lr;
            if (!causal || kA <= qq)      pl[reg] += __expf(accA[reg] * 0.125f);
            if (!causal || kA + 16 <= qq) pl[reg] += __expf(accB[reg] * 0.125f);
        }
    }
#pragma unroll
    for (int reg = 0; reg < 4; ++reg) {
        float v = pl[reg];
        v += __shfl_xor(v, 1); v += __shfl_xor(v, 2);
        v += __shfl_xor(v, 4); v += __shfl_xor(v, 8);
        if (lr == 0) sumL[kh][qi * 16 + lg * 4 + reg] = v;
    }
    __syncthreads();

    float inv_r[4];
#pragma unroll
    for (int reg = 0; reg < 4; ++reg) {
        int row = qi * 16 + lg * 4 + reg;
        inv_r[reg] = 1.0f / (sumL[0][row] + sumL[1][row]);
    }

    // ---- pass 2: recompute scores, write normalized P, accumulate PV
    float* attrow = attnw + ((size_t)((b * H_ + h) * S_ + q0)) * S_;
    const ushort_t* Vbase = Vt + (size_t)n * DH_ * S_;
    f32x4 oacc[2] = {};
    const int dj0 = kh * 2;

    for (int kt = 0; kt < kend; kt += KT) {
        int kcA = kt + kh * 32;
        const ushort_t* kra = Kbase + (size_t)(kcA + lr) * DH_ + lg * 8;
        const ushort_t* krb = kra + (size_t)16 * DH_;
        f32x4 accA = {}, accB = {};
        accA = __builtin_amdgcn_mfma_f32_16x16x32_bf16(qa0, *(const bf16x8*)(kra),      accA, 0, 0, 0);
        accA = __builtin_amdgcn_mfma_f32_16x16x32_bf16(qa1, *(const bf16x8*)(kra + 32), accA, 0, 0, 0);
        accB = __builtin_amdgcn_mfma_f32_16x16x32_bf16(qa0, *(const bf16x8*)(krb),      accB, 0, 0, 0);
        accB = __builtin_amdgcn_mfma_f32_16x16x32_bf16(qa1, *(const bf16x8*)(krb + 32), accB, 0, 0, 0);
#pragma unroll
        for (int reg = 0; reg < 4; ++reg) {
            int qq = qrow0 + reg;
            int kA = kcA + lr;
            float pA = (!causal || kA <= qq)      ? __expf(accA[reg] * 0.125f) * inv_r[reg] : 0.f;
            float pB = (!causal || kA + 16 <= qq) ? __expf(accB[reg] * 0.125f) * inv_r[reg] : 0.f;
            P_lds[qi * 16 + lg * 4 + reg][kh * 32 + lr]      = pA;
            P_lds[qi * 16 + lg * 4 + reg][kh * 32 + 16 + lr] = pB;
        }
        __syncthreads();

        // coalesced float4 copy of P tile -> attnw
#pragma unroll
        for (int cc = 0; cc < 2; ++cc) {
            int ch = tid + cc * 256;
            int row = ch >> 4, col4 = (ch & 15) * 4;
            float4 v = *(const float4*)&P_lds[row][col4];
            *(float4*)&attrow[(size_t)row * S_ + kt + col4] = v;
        }

        // PV MFMA
#pragma unroll
        for (int ks = 0; ks < 2; ++ks) {
            const float* pr = &P_lds[qi * 16 + lr][ks * 32 + lg * 8];
            bf16x8 pa;
#pragma unroll
            for (int j = 0; j < 8; ++j) pa[j] = (__bf16)pr[j];
#pragma unroll
            for (int dj = 0; dj < 2; ++dj) {
                const ushort_t* vr = Vbase + (size_t)((dj0 + dj) * 16 + lr) * S_ + kt + ks * 32 + lg * 8;
                oacc[dj] = __builtin_amdgcn_mfma_f32_16x16x32_bf16(pa, *(const bf16x8*)vr, oacc[dj], 0, 0, 0);
            }
        }
        __syncthreads();
    }

    // zero-fill attnw cols [kend, S)
    if (kend < S_) {
        int rowsz = (S_ - kend) / 4;
        for (int idx = tid; idx < QBLK * rowsz; idx += 256) {
            int row = idx / rowsz, c4 = (idx % rowsz) * 4;
            float4 z = {0.f, 0.f, 0.f, 0.f};
            *(float4*)&attrow[(size_t)row * S_ + kend + c4] = z;
        }
    }

    // out write
#pragma unroll
    for (int dj = 0; dj < 2; ++dj) {
        int d = (dj0 + dj) * 16 + lr;
#pragma unroll
        for (int reg = 0; reg < 4; ++reg) {
            int qq = qrow0 + reg;
            outp[((size_t)b * S_ + qq) * DIM_ + h * DH_ + d] = oacc[dj][reg];
        }
    }
}

extern "C" void kernel_launch(void* const* d_in, const int* in_sizes, int n_in,
                              void* d_out, int out_size, void* d_ws, size_t ws_size,
                              hipStream_t stream) {
    const float* queries = (const float*)d_in[0];
    const float* keys    = (const float*)d_in[1];
    const float* Wq = (const float*)d_in[2];
    const float* bq = (const float*)d_in[3];
    const float* Wk = (const float*)d_in[4];
    const float* bk = (const float*)d_in[5];
    const float* Wv = (const float*)d_in[6];
    const float* bv = (const float*)d_in[7];
    const int*   caus = (const int*)d_in[8];

    char* ws = (char*)d_ws;
    ushort_t* Qin_bf = (ushort_t*)ws;                                  ws += (size_t)B_*S_*DIM_*2;   // 4 MB
    ushort_t* Kin_bf = (ushort_t*)ws;                                  ws += (size_t)B_*S_*DIM_*2;   // 4 MB
    ushort_t* Wqb = (ushort_t*)ws;                                     ws += (size_t)DIM_*DIM_*2;
    ushort_t* Wkb = (ushort_t*)ws;                                     ws += (size_t)DIM_*DIM_*2;
    ushort_t* Wvb = (ushort_t*)ws;                                     ws += (size_t)DIM_*DIM_*2;
    ushort_t* Qh = (ushort_t*)ws;                                      ws += (size_t)H_*B_*S_*DH_*2; // 4 MB
    ushort_t* Kh = (ushort_t*)ws;                                      ws += (size_t)H_*B_*S_*DH_*2; // 4 MB
    ushort_t* Vt = (ushort_t*)ws;                                      ws += (size_t)H_*B_*DH_*S_*2; // 4 MB

    float* outp  = (float*)d_out;
    float* attnw = outp + (size_t)B_ * S_ * DIM_;

    convert_kernel<<<dim3(2048, 5), 256, 0, stream>>>(
        queries, keys, Wq, Wk, Wv, Qin_bf, Kin_bf, Wqb, Wkb, Wvb);

    proj_mfma_kernel<<<dim3(64, 8, 3), 256, 0, stream>>>(
        Qin_bf, Kin_bf, Wqb, bq, Wkb, bk, Wvb, bv, Qh, Kh, Vt);

    attn_mfma_kernel<<<1024, 256, 0, stream>>>(Qh, Kh, Vt, caus, outp, attnw);
}

// Round 4
// 158.139 us; speedup vs baseline: 5.7067x; 1.3381x over previous
//
#include <hip/hip_runtime.h>
#include <math.h>

#define B_ 2
#define S_ 2048
#define DIM_ 512
#define H_ 8
#define DH_ 64
#define QBLK 16
#define KTILE 32
#define PSTRIDE 2056   // 2048 + 8 bf16 pad: row stride 4112B -> banks spread by 4

typedef __bf16 bf16x8 __attribute__((ext_vector_type(8)));
typedef float f32x4 __attribute__((ext_vector_type(4)));
typedef float vf4 __attribute__((ext_vector_type(4)));   // for nontemporal stores
typedef unsigned short ushort_t;
typedef ushort_t ushort8 __attribute__((ext_vector_type(8)));

__device__ __forceinline__ ushort_t f2bf(float f) {
    union { float f; unsigned u; } v; v.f = f;
    unsigned u = v.u;
    return (ushort_t)((u + 0x7FFFu + ((u >> 16) & 1u)) >> 16);
}
__device__ __forceinline__ float bf2f(ushort_t u) {
    union { unsigned u; float f; } v; v.u = ((unsigned)u) << 16;
    return v.f;
}

// ---------------------------------------------------------------------------
// f32 -> bf16 conversion for inputs and weights
// ---------------------------------------------------------------------------
__global__ __launch_bounds__(256) void convert_kernel(
    const float* __restrict__ q, const float* __restrict__ k,
    const float* __restrict__ wq, const float* __restrict__ wk,
    const float* __restrict__ wv,
    ushort_t* qbf, ushort_t* kbf, ushort_t* wqb, ushort_t* wkb, ushort_t* wvb)
{
    const float* src; ushort_t* dst; int n;
    switch (blockIdx.y) {
        case 0: src = q;  dst = qbf; n = B_ * S_ * DIM_; break;
        case 1: src = k;  dst = kbf; n = B_ * S_ * DIM_; break;
        case 2: src = wq; dst = wqb; n = DIM_ * DIM_; break;
        case 3: src = wk; dst = wkb; n = DIM_ * DIM_; break;
        default: src = wv; dst = wvb; n = DIM_ * DIM_; break;
    }
    int i4 = blockIdx.x * 256 + threadIdx.x;
    if (i4 * 4 >= n) return;
    float4 v = ((const float4*)src)[i4];
    ushort4 o;
    o.x = f2bf(v.x); o.y = f2bf(v.y); o.z = f2bf(v.z); o.w = f2bf(v.w);
    ((ushort4*)dst)[i4] = o;
}

// ---------------------------------------------------------------------------
// Projection via MFMA: C = A @ W^T + b. Direct-global fragment loads.
// which 0: queries->Qh (head-major bf16), 1: keys->Kh, 2: keys->Vt (transposed)
// ---------------------------------------------------------------------------
__global__ __launch_bounds__(256) void proj_mfma_kernel(
    const ushort_t* __restrict__ Qin, const ushort_t* __restrict__ Kin,
    const ushort_t* __restrict__ Wqb, const float* __restrict__ bq,
    const ushort_t* __restrict__ Wkb, const float* __restrict__ bk,
    const ushort_t* __restrict__ Wvb, const float* __restrict__ bv,
    ushort_t* __restrict__ Qh, ushort_t* __restrict__ Kh, ushort_t* __restrict__ Vt)
{
    __shared__ float T[64][68];   // transpose staging (which==2 only)

    const int which = blockIdx.z;
    const ushort_t* A = (which == 0) ? Qin : Kin;
    const ushort_t* W = (which == 0) ? Wqb : (which == 1 ? Wkb : Wvb);
    const float* bias = (which == 0) ? bq : (which == 1 ? bk : bv);

    const int r0 = blockIdx.x * 64;
    const int h  = blockIdx.y;
    const int c0 = h * DH_;
    const int tid = threadIdx.x;
    const int w = tid >> 6, l = tid & 63;
    const int lr = l & 15, lg = l >> 4;

    f32x4 acc[4] = {};
    const ushort_t* arow  = A + (size_t)(r0 + w * 16 + lr) * DIM_ + lg * 8;
    const ushort_t* wrow0 = W + (size_t)(c0 + lr) * DIM_ + lg * 8;

#pragma unroll 4
    for (int ks = 0; ks < DIM_ / 32; ++ks) {
        bf16x8 a = *(const bf16x8*)(arow + ks * 32);
#pragma unroll
        for (int ct = 0; ct < 4; ++ct) {
            bf16x8 bfr = *(const bf16x8*)(wrow0 + (size_t)ct * 16 * DIM_ + ks * 32);
            acc[ct] = __builtin_amdgcn_mfma_f32_16x16x32_bf16(a, bfr, acc[ct], 0, 0, 0);
        }
    }

    if (which < 2) {
        ushort_t* OUT = (which == 0) ? Qh : Kh;
#pragma unroll
        for (int ct = 0; ct < 4; ++ct) {
            int d = ct * 16 + lr;
            float bi = bias[c0 + d];
#pragma unroll
            for (int reg = 0; reg < 4; ++reg) {
                int rr = r0 + w * 16 + lg * 4 + reg;
                int bb = rr >> 11, s = rr & (S_ - 1);
                int n = h * B_ + bb;
                OUT[((size_t)n * S_ + s) * DH_ + d] = f2bf(acc[ct][reg] + bi);
            }
        }
    } else {
#pragma unroll
        for (int ct = 0; ct < 4; ++ct) {
            int d = ct * 16 + lr;
            float bi = bias[c0 + d];
#pragma unroll
            for (int reg = 0; reg < 4; ++reg)
                T[w * 16 + lg * 4 + reg][d] = acc[ct][reg] + bi;
        }
        __syncthreads();
        int d = tid & 63, sc = tid >> 6;
        int rr = r0 + sc * 16;
        int bb = rr >> 11, s = rr & (S_ - 1);
        int n = h * B_ + bb;
        ushort8 o[2];
#pragma unroll
        for (int i = 0; i < 16; ++i)
            ((ushort_t*)o)[i] = f2bf(T[sc * 16 + i][d]);
        ushort8* dst = (ushort8*)(Vt + ((size_t)n * DH_ + d) * S_ + s);
        dst[0] = o[0];
        dst[1] = o[1];
    }
}

// ---------------------------------------------------------------------------
// Fused attention, single pass. Block = 16 q-rows x one n=(h*B+b), 4 waves.
// Unnormalized exp(S) row block lives in LDS as bf16; one barrier; then
// normalized write-out + PV (normalization folded into epilogues).
// ---------------------------------------------------------------------------
__global__ __launch_bounds__(256, 2) void attn_mfma_kernel(
    const ushort_t* __restrict__ Qh, const ushort_t* __restrict__ Kh,
    const ushort_t* __restrict__ Vt, const int* __restrict__ causp,
    float* __restrict__ outp, float* __restrict__ attnw)
{
    __shared__ ushort_t Pl[QBLK][PSTRIDE];   // 16 x 2056 x 2B = 65,792 B
    __shared__ float sums[4][QBLK];

    const int bid = blockIdx.x;
    const int swz = (bid & 7) * 256 + (bid >> 3);   // XCD-bijective (2048 = 8*256)
    const int n = swz >> 7;          // head-batch index
    const int qt = swz & 127;
    const int h = n / B_, b = n % B_;
    const int q0 = qt * QBLK;
    const int causal = causp[0];
    const int tid = threadIdx.x;
    const int w = tid >> 6, l = tid & 63;
    const int lr = l & 15, lg = l >> 4;

    const int kmax = causal ? (q0 + QBLK) : S_;
    const int kend = ((kmax + KTILE - 1) / KTILE) * KTILE;

    float* attrow = attnw + ((size_t)((b * H_ + h) * S_ + q0)) * S_;

    // ---- early zero-fill of attnw cols [kend, S): no deps, drains under compute
    if (kend < S_) {
        int zc = (S_ - kend) >> 2;
        vf4 z = {0.f, 0.f, 0.f, 0.f};
        for (int idx = tid; idx < QBLK * zc; idx += 256) {
            int r = idx / zc, c4 = (idx % zc) << 2;
            __builtin_nontemporal_store(z, (vf4*)&attrow[(size_t)r * S_ + kend + c4]);
        }
    }

    // ---- Q fragments (rows q0+lr, dh = lg*8 + {0,32})
    const ushort_t* qrow = Qh + ((size_t)n * S_ + q0 + lr) * DH_ + lg * 8;
    bf16x8 qa0 = *(const bf16x8*)(qrow);
    bf16x8 qa1 = *(const bf16x8*)(qrow + 32);

    const ushort_t* Kbase = Kh + (size_t)n * S_ * DH_;

    // ---- score sweep: wave w handles 32-col tiles t = w, w+4, ...
    float pl[4] = {0.f, 0.f, 0.f, 0.f};
    for (int kc = w * KTILE; kc < kend; kc += 4 * KTILE) {
        const ushort_t* kra = Kbase + (size_t)(kc + lr) * DH_ + lg * 8;
        const ushort_t* krb = kra + (size_t)16 * DH_;
        f32x4 accA = {}, accB = {};
        accA = __builtin_amdgcn_mfma_f32_16x16x32_bf16(qa0, *(const bf16x8*)(kra),      accA, 0, 0, 0);
        accA = __builtin_amdgcn_mfma_f32_16x16x32_bf16(qa1, *(const bf16x8*)(kra + 32), accA, 0, 0, 0);
        accB = __builtin_amdgcn_mfma_f32_16x16x32_bf16(qa0, *(const bf16x8*)(krb),      accB, 0, 0, 0);
        accB = __builtin_amdgcn_mfma_f32_16x16x32_bf16(qa1, *(const bf16x8*)(krb + 32), accB, 0, 0, 0);
#pragma unroll
        for (int reg = 0; reg < 4; ++reg) {
            int row = lg * 4 + reg;
            int qq = q0 + row;
            int kA = kc + lr, kB = kA + 16;
            float eA = (!causal || kA <= qq) ? __expf(accA[reg] * 0.125f) : 0.f;
            float eB = (!causal || kB <= qq) ? __expf(accB[reg] * 0.125f) : 0.f;
            pl[reg] += eA + eB;
            Pl[row][kA] = f2bf(eA);
            Pl[row][kB] = f2bf(eB);
        }
    }

    // per-row sums: reduce over the 16 lr-lanes, slot per wave
#pragma unroll
    for (int reg = 0; reg < 4; ++reg) {
        float v = pl[reg];
        v += __shfl_xor(v, 1); v += __shfl_xor(v, 2);
        v += __shfl_xor(v, 4); v += __shfl_xor(v, 8);
        if (lr == 0) sums[w][lg * 4 + reg] = v;
    }
    __syncthreads();   // the ONLY barrier

    // ---- normalized write-out: row = tid>>4, 16 threads per row
    {
        int row = tid >> 4, cl = (tid & 15) << 2;
        float invw = 1.f / (sums[0][row] + sums[1][row] + sums[2][row] + sums[3][row]);
        float* ar = attrow + (size_t)row * S_;
        for (int c = cl; c < kend; c += 64) {
            ushort4 pv = *(const ushort4*)&Pl[row][c];
            vf4 o;
            o.x = bf2f(pv.x) * invw;
            o.y = bf2f(pv.y) * invw;
            o.z = bf2f(pv.z) * invw;
            o.w = bf2f(pv.w) * invw;
            __builtin_nontemporal_store(o, (vf4*)&ar[c]);
        }
    }

    // ---- PV from LDS bf16 (A-frag direct), normalize at epilogue
    float inv_r[4];
#pragma unroll
    for (int reg = 0; reg < 4; ++reg) {
        int row = lg * 4 + reg;
        inv_r[reg] = 1.f / (sums[0][row] + sums[1][row] + sums[2][row] + sums[3][row]);
    }
    f32x4 oacc = {};
    const ushort_t* Vbase = Vt + (size_t)n * DH_ * S_ + (size_t)(w * 16 + lr) * S_;
    for (int kt = 0; kt < kend; kt += KTILE) {
        bf16x8 pa = *(const bf16x8*)&Pl[lr][kt + lg * 8];
        bf16x8 vb = *(const bf16x8*)(Vbase + kt + lg * 8);
        oacc = __builtin_amdgcn_mfma_f32_16x16x32_bf16(pa, vb, oacc, 0, 0, 0);
    }
#pragma unroll
    for (int reg = 0; reg < 4; ++reg) {
        int qq = q0 + lg * 4 + reg;
        __builtin_nontemporal_store(oacc[reg] * inv_r[reg],
            &outp[((size_t)b * S_ + qq) * DIM_ + h * DH_ + w * 16 + lr]);
    }
}

extern "C" void kernel_launch(void* const* d_in, const int* in_sizes, int n_in,
                              void* d_out, int out_size, void* d_ws, size_t ws_size,
                              hipStream_t stream) {
    const float* queries = (const float*)d_in[0];
    const float* keys    = (const float*)d_in[1];
    const float* Wq = (const float*)d_in[2];
    const float* bq = (const float*)d_in[3];
    const float* Wk = (const float*)d_in[4];
    const float* bk = (const float*)d_in[5];
    const float* Wv = (const float*)d_in[6];
    const float* bv = (const float*)d_in[7];
    const int*   caus = (const int*)d_in[8];

    char* ws = (char*)d_ws;
    ushort_t* Qin_bf = (ushort_t*)ws;  ws += (size_t)B_*S_*DIM_*2;
    ushort_t* Kin_bf = (ushort_t*)ws;  ws += (size_t)B_*S_*DIM_*2;
    ushort_t* Wqb = (ushort_t*)ws;     ws += (size_t)DIM_*DIM_*2;
    ushort_t* Wkb = (ushort_t*)ws;     ws += (size_t)DIM_*DIM_*2;
    ushort_t* Wvb = (ushort_t*)ws;     ws += (size_t)DIM_*DIM_*2;
    ushort_t* Qh = (ushort_t*)ws;      ws += (size_t)H_*B_*S_*DH_*2;
    ushort_t* Kh = (ushort_t*)ws;      ws += (size_t)H_*B_*S_*DH_*2;
    ushort_t* Vt = (ushort_t*)ws;      ws += (size_t)H_*B_*DH_*S_*2;

    float* outp  = (float*)d_out;
    float* attnw = outp + (size_t)B_ * S_ * DIM_;

    convert_kernel<<<dim3(2048, 5), 256, 0, stream>>>(
        queries, keys, Wq, Wk, Wv, Qin_bf, Kin_bf, Wqb, Wkb, Wvb);

    proj_mfma_kernel<<<dim3(64, 8, 3), 256, 0, stream>>>(
        Qin_bf, Kin_bf, Wqb, bq, Wkb, bk, Wvb, bv, Qh, Kh, Vt);

    attn_mfma_kernel<<<2048, 256, 0, stream>>>(Qh, Kh, Vt, caus, outp, attnw);
}

// Round 5
// 156.383 us; speedup vs baseline: 5.7708x; 1.0112x over previous
//
#include <hip/hip_runtime.h>
#include <math.h>

#define B_ 2
#define S_ 2048
#define DIM_ 512
#define H_ 8
#define DH_ 64
#define QBLK 16
#define KTILE 32
#define PSTRIDE 2056   // 2048 + 8 bf16 pad

typedef __bf16 bf16x8 __attribute__((ext_vector_type(8)));
typedef float f32x4 __attribute__((ext_vector_type(4)));
typedef float vf4 __attribute__((ext_vector_type(4)));
typedef unsigned short ushort_t;
typedef ushort_t ushort8 __attribute__((ext_vector_type(8)));

__device__ __forceinline__ ushort_t f2bf(float f) {
    union { float f; unsigned u; } v; v.f = f;
    unsigned u = v.u;
    return (ushort_t)((u + 0x7FFFu + ((u >> 16) & 1u)) >> 16);
}
__device__ __forceinline__ float bf2f(ushort_t u) {
    union { unsigned u; float f; } v; v.u = ((unsigned)u) << 16;
    return v.f;
}

// ---------------------------------------------------------------------------
// f32 -> bf16 conversion for inputs and weights
// ---------------------------------------------------------------------------
__global__ __launch_bounds__(256) void convert_kernel(
    const float* __restrict__ q, const float* __restrict__ k,
    const float* __restrict__ wq, const float* __restrict__ wk,
    const float* __restrict__ wv,
    ushort_t* qbf, ushort_t* kbf, ushort_t* wqb, ushort_t* wkb, ushort_t* wvb)
{
    const float* src; ushort_t* dst; int n;
    switch (blockIdx.y) {
        case 0: src = q;  dst = qbf; n = B_ * S_ * DIM_; break;
        case 1: src = k;  dst = kbf; n = B_ * S_ * DIM_; break;
        case 2: src = wq; dst = wqb; n = DIM_ * DIM_; break;
        case 3: src = wk; dst = wkb; n = DIM_ * DIM_; break;
        default: src = wv; dst = wvb; n = DIM_ * DIM_; break;
    }
    int i4 = blockIdx.x * 256 + threadIdx.x;
    if (i4 * 4 >= n) return;
    float4 v = ((const float4*)src)[i4];
    ushort4 o;
    o.x = f2bf(v.x); o.y = f2bf(v.y); o.z = f2bf(v.z); o.w = f2bf(v.w);
    ((ushort4*)dst)[i4] = o;
}

// ---------------------------------------------------------------------------
// Projection via MFMA: C = A @ W^T + b. 128 rows x 64 cols per block,
// 32 rows per wave (B-fragment reused across 2 row-groups).
// which 0: queries->Qh, 1: keys->Kh, 2: keys->Vt (transposed)
// ---------------------------------------------------------------------------
__global__ __launch_bounds__(256) void proj_mfma_kernel(
    const ushort_t* __restrict__ Qin, const ushort_t* __restrict__ Kin,
    const ushort_t* __restrict__ Wqb, const float* __restrict__ bq,
    const ushort_t* __restrict__ Wkb, const float* __restrict__ bk,
    const ushort_t* __restrict__ Wvb, const float* __restrict__ bv,
    ushort_t* __restrict__ Qh, ushort_t* __restrict__ Kh, ushort_t* __restrict__ Vt)
{
    __shared__ float T[128][68];   // transpose staging (which==2 only), 34.8 KB

    const int which = blockIdx.z;
    const ushort_t* A = (which == 0) ? Qin : Kin;
    const ushort_t* W = (which == 0) ? Wqb : (which == 1 ? Wkb : Wvb);
    const float* bias = (which == 0) ? bq : (which == 1 ? bk : bv);

    const int r0 = blockIdx.x * 128;           // 2048%128==0: block within one batch
    const int h  = blockIdx.y;
    const int c0 = h * DH_;
    const int tid = threadIdx.x;
    const int w = tid >> 6, l = tid & 63;
    const int lr = l & 15, lg = l >> 4;

    f32x4 acc[2][4] = {};
    const ushort_t* arow0 = A + (size_t)(r0 + w * 32 + lr) * DIM_ + lg * 8;
    const ushort_t* arow1 = arow0 + (size_t)16 * DIM_;
    const ushort_t* wrow0 = W + (size_t)(c0 + lr) * DIM_ + lg * 8;

#pragma unroll 4
    for (int ks = 0; ks < DIM_ / 32; ++ks) {
        bf16x8 a0 = *(const bf16x8*)(arow0 + ks * 32);
        bf16x8 a1 = *(const bf16x8*)(arow1 + ks * 32);
#pragma unroll
        for (int ct = 0; ct < 4; ++ct) {
            bf16x8 bfr = *(const bf16x8*)(wrow0 + (size_t)ct * 16 * DIM_ + ks * 32);
            acc[0][ct] = __builtin_amdgcn_mfma_f32_16x16x32_bf16(a0, bfr, acc[0][ct], 0, 0, 0);
            acc[1][ct] = __builtin_amdgcn_mfma_f32_16x16x32_bf16(a1, bfr, acc[1][ct], 0, 0, 0);
        }
    }

    const int bb = r0 >> 11;          // batch index (constant per block)
    const int s0 = r0 & (S_ - 1);
    const int n = h * B_ + bb;

    if (which < 2) {
        ushort_t* OUT = (which == 0) ? Qh : Kh;
#pragma unroll
        for (int rg = 0; rg < 2; ++rg) {
#pragma unroll
            for (int ct = 0; ct < 4; ++ct) {
                int d = ct * 16 + lr;
                float bi = bias[c0 + d];
#pragma unroll
                for (int reg = 0; reg < 4; ++reg) {
                    int s = s0 + w * 32 + rg * 16 + lg * 4 + reg;
                    OUT[((size_t)n * S_ + s) * DH_ + d] = f2bf(acc[rg][ct][reg] + bi);
                }
            }
        }
    } else {
#pragma unroll
        for (int rg = 0; rg < 2; ++rg) {
#pragma unroll
            for (int ct = 0; ct < 4; ++ct) {
                int d = ct * 16 + lr;
                float bi = bias[c0 + d];
#pragma unroll
                for (int reg = 0; reg < 4; ++reg)
                    T[w * 32 + rg * 16 + lg * 4 + reg][d] = acc[rg][ct][reg] + bi;
            }
        }
        __syncthreads();
        int d = tid & 63, sc = tid >> 6;    // sc 0..3, rows sc*32..sc*32+31
        ushort8 o[4];
#pragma unroll
        for (int i = 0; i < 32; ++i)
            ((ushort_t*)o)[i] = f2bf(T[sc * 32 + i][d]);
        ushort8* dst = (ushort8*)(Vt + ((size_t)n * DH_ + d) * S_ + s0 + sc * 32);
        dst[0] = o[0]; dst[1] = o[1]; dst[2] = o[2]; dst[3] = o[3];
    }
}

// ---------------------------------------------------------------------------
// Fused attention, single pass. Block = 16 q-rows x one n=(h*B+b), 4 waves.
// Unnormalized exp(S) in LDS bf16; one barrier; normalized write-out + PV.
// Heavy blocks (large kend) dispatched first (LPT).
// ---------------------------------------------------------------------------
__global__ __launch_bounds__(256, 2) void attn_mfma_kernel(
    const ushort_t* __restrict__ Qh, const ushort_t* __restrict__ Kh,
    const ushort_t* __restrict__ Vt, const int* __restrict__ causp,
    float* __restrict__ outp, float* __restrict__ attnw)
{
    __shared__ ushort_t Pl[QBLK][PSTRIDE];   // 65,792 B
    __shared__ float sums[4][QBLK];

    const int bid = blockIdx.x;
    const int swz = (bid & 7) * 256 + (bid >> 3);   // XCD-bijective (2048 = 8*256)
    const int n = swz >> 7;                  // head-batch index
    const int qt = 127 - (swz & 127);        // LPT: heaviest (largest kend) first
    const int h = n / B_, b = n % B_;
    const int q0 = qt * QBLK;
    const int causal = causp[0];
    const int tid = threadIdx.x;
    const int w = tid >> 6, l = tid & 63;
    const int lr = l & 15, lg = l >> 4;

    const int kmax = causal ? (q0 + QBLK) : S_;
    const int kend = ((kmax + KTILE - 1) / KTILE) * KTILE;

    float* attrow = attnw + ((size_t)((b * H_ + h) * S_ + q0)) * S_;

    // ---- early zero-fill of attnw cols [kend, S): no deps, drains under compute
    if (kend < S_) {
        int zc = (S_ - kend) >> 2;
        vf4 z = {0.f, 0.f, 0.f, 0.f};
        for (int idx = tid; idx < QBLK * zc; idx += 256) {
            int r = idx / zc, c4 = (idx % zc) << 2;
            __builtin_nontemporal_store(z, (vf4*)&attrow[(size_t)r * S_ + kend + c4]);
        }
    }

    // ---- Q fragments (rows q0+lr, dh = lg*8 + {0,32})
    const ushort_t* qrow = Qh + ((size_t)n * S_ + q0 + lr) * DH_ + lg * 8;
    bf16x8 qa0 = *(const bf16x8*)(qrow);
    bf16x8 qa1 = *(const bf16x8*)(qrow + 32);

    const ushort_t* Kbase = Kh + (size_t)n * S_ * DH_;

    // ---- score sweep: wave w handles 32-col tiles t = w, w+4, ...
    float pl[4] = {0.f, 0.f, 0.f, 0.f};
    for (int kc = w * KTILE; kc < kend; kc += 4 * KTILE) {
        const ushort_t* kra = Kbase + (size_t)(kc + lr) * DH_ + lg * 8;
        const ushort_t* krb = kra + (size_t)16 * DH_;
        f32x4 accA = {}, accB = {};
        accA = __builtin_amdgcn_mfma_f32_16x16x32_bf16(qa0, *(const bf16x8*)(kra),      accA, 0, 0, 0);
        accA = __builtin_amdgcn_mfma_f32_16x16x32_bf16(qa1, *(const bf16x8*)(kra + 32), accA, 0, 0, 0);
        accB = __builtin_amdgcn_mfma_f32_16x16x32_bf16(qa0, *(const bf16x8*)(krb),      accB, 0, 0, 0);
        accB = __builtin_amdgcn_mfma_f32_16x16x32_bf16(qa1, *(const bf16x8*)(krb + 32), accB, 0, 0, 0);
#pragma unroll
        for (int reg = 0; reg < 4; ++reg) {
            int row = lg * 4 + reg;
            int qq = q0 + row;
            int kA = kc + lr, kB = kA + 16;
            float eA = (!causal || kA <= qq) ? __expf(accA[reg] * 0.125f) : 0.f;
            float eB = (!causal || kB <= qq) ? __expf(accB[reg] * 0.125f) : 0.f;
            pl[reg] += eA + eB;
            __bf16 vA = (__bf16)eA, vB = (__bf16)eB;
            Pl[row][kA] = *(ushort_t*)&vA;
            Pl[row][kB] = *(ushort_t*)&vB;
        }
    }

    // per-row sums: reduce over the 16 lr-lanes, slot per wave
#pragma unroll
    for (int reg = 0; reg < 4; ++reg) {
        float v = pl[reg];
        v += __shfl_xor(v, 1); v += __shfl_xor(v, 2);
        v += __shfl_xor(v, 4); v += __shfl_xor(v, 8);
        if (lr == 0) sums[w][lg * 4 + reg] = v;
    }
    __syncthreads();   // the ONLY barrier

    // ---- normalized write-out: one row per wave-iteration, 64 lanes x ushort8
    //      -> 2 KB contiguous global burst, all-bank LDS reads
#pragma unroll
    for (int rr = 0; rr < 4; ++rr) {
        int row = w * 4 + rr;
        float invw = 1.f / (sums[0][row] + sums[1][row] + sums[2][row] + sums[3][row]);
        float* ar = attrow + (size_t)row * S_;
        for (int c = l * 8; c < kend; c += 512) {
            ushort8 pv = *(const ushort8*)&Pl[row][c];
            vf4 o0, o1;
            o0.x = bf2f(pv[0]) * invw; o0.y = bf2f(pv[1]) * invw;
            o0.z = bf2f(pv[2]) * invw; o0.w = bf2f(pv[3]) * invw;
            o1.x = bf2f(pv[4]) * invw; o1.y = bf2f(pv[5]) * invw;
            o1.z = bf2f(pv[6]) * invw; o1.w = bf2f(pv[7]) * invw;
            __builtin_nontemporal_store(o0, (vf4*)&ar[c]);
            __builtin_nontemporal_store(o1, (vf4*)&ar[c + 4]);
        }
    }

    // ---- PV from LDS bf16 (A-frag direct), normalize at epilogue
    float inv_r[4];
#pragma unroll
    for (int reg = 0; reg < 4; ++reg) {
        int row = lg * 4 + reg;
        inv_r[reg] = 1.f / (sums[0][row] + sums[1][row] + sums[2][row] + sums[3][row]);
    }
    f32x4 oacc = {};
    const ushort_t* Vbase = Vt + (size_t)n * DH_ * S_ + (size_t)(w * 16 + lr) * S_;
    for (int kt = 0; kt < kend; kt += KTILE) {
        bf16x8 pa = *(const bf16x8*)&Pl[lr][kt + lg * 8];
        bf16x8 vb = *(const bf16x8*)(Vbase + kt + lg * 8);
        oacc = __builtin_amdgcn_mfma_f32_16x16x32_bf16(pa, vb, oacc, 0, 0, 0);
    }
#pragma unroll
    for (int reg = 0; reg < 4; ++reg) {
        int qq = q0 + lg * 4 + reg;
        __builtin_nontemporal_store(oacc[reg] * inv_r[reg],
            &outp[((size_t)b * S_ + qq) * DIM_ + h * DH_ + w * 16 + lr]);
    }
}

extern "C" void kernel_launch(void* const* d_in, const int* in_sizes, int n_in,
                              void* d_out, int out_size, void* d_ws, size_t ws_size,
                              hipStream_t stream) {
    const float* queries = (const float*)d_in[0];
    const float* keys    = (const float*)d_in[1];
    const float* Wq = (const float*)d_in[2];
    const float* bq = (const float*)d_in[3];
    const float* Wk = (const float*)d_in[4];
    const float* bk = (const float*)d_in[5];
    const float* Wv = (const float*)d_in[6];
    const float* bv = (const float*)d_in[7];
    const int*   caus = (const int*)d_in[8];

    char* ws = (char*)d_ws;
    ushort_t* Qin_bf = (ushort_t*)ws;  ws += (size_t)B_*S_*DIM_*2;
    ushort_t* Kin_bf = (ushort_t*)ws;  ws += (size_t)B_*S_*DIM_*2;
    ushort_t* Wqb = (ushort_t*)ws;     ws += (size_t)DIM_*DIM_*2;
    ushort_t* Wkb = (ushort_t*)ws;     ws += (size_t)DIM_*DIM_*2;
    ushort_t* Wvb = (ushort_t*)ws;     ws += (size_t)DIM_*DIM_*2;
    ushort_t* Qh = (ushort_t*)ws;      ws += (size_t)H_*B_*S_*DH_*2;
    ushort_t* Kh = (ushort_t*)ws;      ws += (size_t)H_*B_*S_*DH_*2;
    ushort_t* Vt = (ushort_t*)ws;      ws += (size_t)H_*B_*DH_*S_*2;

    float* outp  = (float*)d_out;
    float* attnw = outp + (size_t)B_ * S_ * DIM_;

    convert_kernel<<<dim3(2048, 5), 256, 0, stream>>>(
        queries, keys, Wq, Wk, Wv, Qin_bf, Kin_bf, Wqb, Wkb, Wvb);

    proj_mfma_kernel<<<dim3(32, 8, 3), 256, 0, stream>>>(
        Qin_bf, Kin_bf, Wqb, bq, Wkb, bk, Wvb, bv, Qh, Kh, Vt);

    attn_mfma_kernel<<<2048, 256, 0, stream>>>(Qh, Kh, Vt, caus, outp, attnw);
}